// Round 9
// baseline (4510.913 us; speedup 1.0000x reference)
//
#include <hip/hip_runtime.h>

typedef unsigned int  u32;
typedef unsigned long long u64;
typedef unsigned short u16;
typedef short s16x8 __attribute__((ext_vector_type(8)));
typedef float f32x4 __attribute__((ext_vector_type(4)));
typedef u32 u32x2 __attribute__((ext_vector_type(2)));
typedef u32 u32x4 __attribute__((ext_vector_type(4)));

// Problem constants
#define BB 32
#define TT 512
#define HH 512
#define GG 1536          // 3H
#define MM 16384         // B*T

__device__ __forceinline__ u16 f2bf(float f) {
  u32 u = __builtin_bit_cast(u32, f);
  u = u + 0x7FFFu + ((u >> 16) & 1u);   // RNE
  return (u16)(u >> 16);
}
__device__ __forceinline__ float bf2f(u16 h) {
  return __builtin_bit_cast(float, (u32)h << 16);
}
__device__ __forceinline__ float sigmoidf_(float x) { return 1.f / (1.f + __expf(-x)); }
__device__ __forceinline__ float tanhf_(float x)    { return 1.f - 2.f / (__expf(2.f * x) + 1.f); }

// ---------------------------------------------------------------------------
// Fragment layout convention (mfma_f32_16x16x32_bf16), used consistently
// everywhere (any consistent K-permutation of A and B cancels):
//   A (MxK): lane l elem j -> A[16*mb + (l&15)][32*kb + (l>>4)*4 + (j&3) + 16*(j>>2)]
//   B (KxN): lane l elem j -> B[32*kb + (l>>4)*4 + (j&3) + 16*(j>>2)][16*nb + (l&15)]
//   D:       lane l reg  r -> D[(l>>4)*4 + r][l&15]            (m89-verified)
// ---------------------------------------------------------------------------

struct PrepP {
  const float *ctx;
  const float *wih0, *whh0, *bih0, *bhh0, *wih0r, *whh0r, *bih0r, *bhh0r;
  const float *wih1, *whh1, *bih1, *bhh1, *wih1r, *whh1r, *bih1r, *bhh1r;
  u16 *a0f, *w0f, *w1f, *whh;
  float *bgx, *bhn;
  u64 *hexq;
};

__global__ void prep_kernel(PrepP P) {
  const size_t NA0 = (size_t)MM * 512;          // A0 frags
  const size_t NW0 = (size_t)3072 * 512;        // W0 frags
  const size_t NW1 = (size_t)3072 * 1024;       // W1 frags
  const size_t NWH = (size_t)2 * 2 * GG * HH;   // w_hh bf16 copies
  const size_t NBG = 2 * 2 * (size_t)GG;
  const size_t NBN = 2 * 2 * (size_t)HH;
  const size_t NHX = 65536;                     // 2 recurs x 32768 u64 tagged slots
  const size_t TOTAL = NA0 + NW0 + NW1 + NWH + NBG + NBN + NHX;
  size_t stride = (size_t)gridDim.x * blockDim.x;
  for (size_t i = (size_t)blockIdx.x * blockDim.x + threadIdx.x; i < TOTAL; i += stride) {
    size_t e = i;
    if (e < NA0) {
      int j = e & 7, l = (e >> 3) & 63, kb = (e >> 9) & 15, mb = (int)(e >> 13);
      int m = mb * 16 + (l & 15);
      int k = kb * 32 + ((l >> 4) << 2) + (j & 3) + ((j >> 2) << 4);
      P.a0f[e] = f2bf(P.ctx[(size_t)m * 512 + k]);
      continue;
    }
    e -= NA0;
    if (e < NW0) {
      int j = e & 7, l = (e >> 3) & 63, kb = (e >> 9) & 15, nb = (int)(e >> 13);
      int n = nb * 16 + (l & 15);
      int d = (n >= GG) ? 1 : 0, g = n - d * GG;
      int k = kb * 32 + ((l >> 4) << 2) + (j & 3) + ((j >> 2) << 4);
      const float* src = d ? P.wih0r : P.wih0;
      P.w0f[e] = f2bf(src[(size_t)g * 512 + k]);
      continue;
    }
    e -= NW0;
    if (e < NW1) {
      int j = e & 7, l = (e >> 3) & 63, kb = (e >> 9) & 31, nb = (int)(e >> 14);
      int n = nb * 16 + (l & 15);
      int d = (n >= GG) ? 1 : 0, g = n - d * GG;
      int k = kb * 32 + ((l >> 4) << 2) + (j & 3) + ((j >> 2) << 4);
      const float* src = d ? P.wih1r : P.wih1;
      P.w1f[e] = f2bf(src[(size_t)g * 1024 + k]);
      continue;
    }
    e -= NW1;
    if (e < NWH) {
      size_t per = (size_t)GG * HH;
      int ld = (int)(e / per); size_t sub = e % per;
      const float* src = (ld == 0) ? P.whh0 : (ld == 1) ? P.whh0r : (ld == 2) ? P.whh1 : P.whh1r;
      P.whh[e] = f2bf(src[sub]);
      continue;
    }
    e -= NWH;
    if (e < NBG) {
      int ld = (int)(e / GG), g = (int)(e % GG);
      const float* bi = (ld == 0) ? P.bih0 : (ld == 1) ? P.bih0r : (ld == 2) ? P.bih1 : P.bih1r;
      const float* bh = (ld == 0) ? P.bhh0 : (ld == 1) ? P.bhh0r : (ld == 2) ? P.bhh1 : P.bhh1r;
      P.bgx[e] = bi[g] + ((g < 1024) ? bh[g] : 0.f);
      continue;
    }
    e -= NBG;
    if (e < NBN) {
      int ld = (int)(e / HH), u = (int)(e % HH);
      const float* bh = (ld == 0) ? P.bhh0 : (ld == 1) ? P.bhh0r : (ld == 2) ? P.bhh1 : P.bhh1r;
      P.bhn[e] = bh[1024 + u];
      continue;
    }
    e -= NBN;
    if (e < NHX) { P.hexq[e] = 0ull; continue; }   // tags=0: never matches expected 1..511
  }
}

// ---------------------------------------------------------------------------
// Projection GEMM (unchanged, proven): C[16384][3072] = A*W, bf16 MFMA.
// ---------------------------------------------------------------------------
template<bool GXF32>
__global__ __launch_bounds__(256, 2) void proj_kernel(const u16* __restrict__ A,
                                                      const u16* __restrict__ W,
                                                      void* __restrict__ gx, int KB) {
  __shared__ uint4 As4[512];
  __shared__ uint4 Bs4[512];
  const int tid = threadIdx.x;
  const int bm = blockIdx.x, bn = blockIdx.y;
  const int l = tid & 63, w = tid >> 6, wm = w >> 1, wn = w & 1;

  f32x4 acc[4][4];
#pragma unroll
  for (int i = 0; i < 4; ++i)
#pragma unroll
    for (int j = 0; j < 4; ++j) acc[i][j] = f32x4{0.f, 0.f, 0.f, 0.f};

  const uint4* GA = (const uint4*)A;
  const uint4* GB = (const uint4*)W;

  for (int kt = 0; kt < KB; ++kt) {
    __syncthreads();
#pragma unroll
    for (int c = 0; c < 2; ++c) {
      int idx = tid * 2 + c;
      int blk = idx >> 6, pos = idx & 63;
      As4[idx] = GA[((size_t)(bm * 8 + blk) * KB + kt) * 64 + pos];
      Bs4[idx] = GB[((size_t)(bn * 8 + blk) * KB + kt) * 64 + pos];
    }
    __syncthreads();
    s16x8 av[4], bv[4];
#pragma unroll
    for (int mf = 0; mf < 4; ++mf) av[mf] = ((const s16x8*)As4)[(wm * 4 + mf) * 64 + l];
#pragma unroll
    for (int nf = 0; nf < 4; ++nf) bv[nf] = ((const s16x8*)Bs4)[(wn * 4 + nf) * 64 + l];
#pragma unroll
    for (int mf = 0; mf < 4; ++mf)
#pragma unroll
      for (int nf = 0; nf < 4; ++nf)
        acc[mf][nf] = __builtin_amdgcn_mfma_f32_16x16x32_bf16(av[mf], bv[nf], acc[mf][nf], 0, 0, 0);
  }

#pragma unroll
  for (int mf = 0; mf < 4; ++mf)
#pragma unroll
    for (int nf = 0; nf < 4; ++nf)
#pragma unroll
      for (int r = 0; r < 4; ++r) {
        int m = bm * 128 + wm * 64 + mf * 16 + (l >> 4) * 4 + r;
        int n = bn * 128 + wn * 64 + nf * 16 + (l & 15);
        int b = m >> 9, t = m & 511;
        int d = (n >= GG) ? 1 : 0, g = n - d * GG;
        size_t o = ((size_t)(d * TT + t) * BB + b) * GG + g;
        float v = acc[mf][nf][r];
        if (GXF32) ((float*)gx)[o] = v;
        else       ((u16*)gx)[o] = f2bf(v);
      }
}

// ---------------------------------------------------------------------------
// Recurrence: 32 WGs (16/dir).  Tagged-u64-atomic transport: each 8B packet =
// {tag(sig+1) | 2xbf16 h}.  Producer: 2 relaxed atomic u64 stores (fire and
// forget — atomicity makes packets self-validating, no ack/flag/fence).
// Consumer: polls its 64 input packets with relaxed agent atomic u64 loads
// (the proven-fresh primitive); on tag match the h data is already in regs.
// Double-buffer + full-mesh within nt-half -> skew<=2, overwrite-safe.
// Slot index: [buf(2)][d(2)][q=s*4+uh*2+w (64)][nt(2)][lane(64)] u64.
// ---------------------------------------------------------------------------
template<bool GXF32, bool YF32>
__global__ __launch_bounds__(256, 1) void recur_kernel(
    const void* __restrict__ gx_, const u16* __restrict__ whh,
    const float* __restrict__ bgx, const float* __restrict__ bhn_,
    void* __restrict__ yout, float* __restrict__ finals,
    u64* __restrict__ hex) {
  const int wg = blockIdx.x, d = wg >> 4, s = wg & 15;
  const int tid = threadIdx.x, l = tid & 63, w = tid >> 6;
  const int nt = w & 1, uh = w >> 1;
  const int l4 = l >> 4, lm = l & 15;
  const int b = nt * 16 + lm;
  const int u0 = s * 32 + uh * 16 + l4 * 4;   // first of this lane's 4 h-units

  // --- w_hh A-fragments into registers ---
  s16x8 af[3][16];
  const u16* wd = whh + (size_t)d * (GG * HH);
#pragma unroll
  for (int g = 0; g < 3; ++g) {
    const int row = g * 512 + s * 32 + uh * 16 + lm;   // A-side row uses lane&15
    const u16* rp = wd + (size_t)row * 512 + l4 * 4;
#pragma unroll
    for (int ks = 0; ks < 16; ++ks) {
      u32 lo0 = *(const u32*)(rp + ks * 32);
      u32 lo1 = *(const u32*)(rp + ks * 32 + 2);
      u32 hi0 = *(const u32*)(rp + ks * 32 + 16);
      u32 hi1 = *(const u32*)(rp + ks * 32 + 18);
      u32x4 t4; t4.x = lo0; t4.y = lo1; t4.z = hi0; t4.w = hi1;
      af[g][ks] = __builtin_bit_cast(s16x8, t4);
    }
  }
  float bgr[4], bgz[4], bgn[4], bhn[4];
#pragma unroll
  for (int r = 0; r < 4; ++r) {
    bgr[r] = bgx[d * GG + 0 * 512 + u0 + r];
    bgz[r] = bgx[d * GG + 1 * 512 + u0 + r];
    bgn[r] = bgx[d * GG + 2 * 512 + u0 + r];
    bhn[r] = bhn_[d * HH + u0 + r];
  }
  float h[4] = {0.f, 0.f, 0.f, 0.f};

  // slot bases (u64 indices): buf stride 16384, d stride 8192, q stride 128
  const u32 wq = (u32)(s * 4 + uh * 2);                       // producer q (w added)
  const u32 wb0 = (u32)(d * 8192 + wq * 128 + nt * 64 + l);   // + buf*16384
  const u32 rb0 = (u32)(d * 8192 + nt * 64 + l);              // + buf*16384 + q*128

  // gx registers, prologue load for sig=0
  float gxr[4], gxz[4], gxn[4];
  {
    const int t0 = d ? 511 : 0;
    const size_t base = ((size_t)(d * TT + t0) * BB + b) * GG + u0;
    if (GXF32) {
      const float* Gp = (const float*)gx_ + base;
      f32x4 vr = *(const f32x4*)(Gp);
      f32x4 vz = *(const f32x4*)(Gp + 512);
      f32x4 vn = *(const f32x4*)(Gp + 1024);
#pragma unroll
      for (int r = 0; r < 4; ++r) { gxr[r] = vr[r]; gxz[r] = vz[r]; gxn[r] = vn[r]; }
    } else {
      const u32* Gp = (const u32*)((const u16*)gx_ + base);
      u32 vr0 = Gp[0], vr1 = Gp[1], vz0 = Gp[256], vz1 = Gp[257], vn0 = Gp[512], vn1 = Gp[513];
      gxr[0] = bf2f((u16)vr0); gxr[1] = bf2f((u16)(vr0 >> 16)); gxr[2] = bf2f((u16)vr1); gxr[3] = bf2f((u16)(vr1 >> 16));
      gxz[0] = bf2f((u16)vz0); gxz[1] = bf2f((u16)(vz0 >> 16)); gxz[2] = bf2f((u16)vz1); gxz[3] = bf2f((u16)(vz1 >> 16));
      gxn[0] = bf2f((u16)vn0); gxn[1] = bf2f((u16)(vn0 >> 16)); gxn[2] = bf2f((u16)vn1); gxn[3] = bf2f((u16)(vn1 >> 16));
    }
  }

  for (int sig = 0; sig < 512; ++sig) {
    const int t = d ? (511 - sig) : sig;

    f32x4 a0 = {0.f, 0.f, 0.f, 0.f}, a1 = a0, a2 = a0;
    if (sig > 0) {
      // 1. poll+load: 64 tagged u64 packets from buf[sig&1]; accept when all
      //    tags == sig (exact).  Data rides with the tags — no second phase.
      const u32 cb = (u32)(sig & 1) * 16384u + rb0;
      const u32 exp = (u32)sig;
      u64 v[64];
      while (true) {
#pragma unroll
        for (int q = 0; q < 64; ++q)
          v[q] = __hip_atomic_load(hex + cb + (u32)q * 128u,
                                   __ATOMIC_RELAXED, __HIP_MEMORY_SCOPE_AGENT);
        u32 good = 1u;
#pragma unroll
        for (int q = 0; q < 64; ++q)
          good &= (u32)((u32)(v[q] >> 32) == exp);
        if (__all((int)good)) break;
      }
      __builtin_amdgcn_sched_barrier(0);

      // 2. MFMA: fragment ks <- {q=ks*4+0..3} data dwords
#pragma unroll
      for (int ks = 0; ks < 16; ++ks) {
        u32x4 t4;
        t4.x = (u32)v[ks * 4 + 0];   // uh'=0, units l4*4+0..1
        t4.y = (u32)v[ks * 4 + 1];   // uh'=0, units l4*4+2..3
        t4.z = (u32)v[ks * 4 + 2];   // uh'=1, units 16+l4*4+0..1
        t4.w = (u32)v[ks * 4 + 3];   // uh'=1, units 16+l4*4+2..3
        s16x8 bv = __builtin_bit_cast(s16x8, t4);
        a0 = __builtin_amdgcn_mfma_f32_16x16x32_bf16(af[0][ks], bv, a0, 0, 0, 0);
        a1 = __builtin_amdgcn_mfma_f32_16x16x32_bf16(af[1][ks], bv, a1, 0, 0, 0);
        a2 = __builtin_amdgcn_mfma_f32_16x16x32_bf16(af[2][ks], bv, a2, 0, 0, 0);
      }
    }

    // 3. gates
    u16 hb16[4];
#pragma unroll
    for (int r = 0; r < 4; ++r) {
      float rr = sigmoidf_(gxr[r] + bgr[r] + a0[r]);
      float zz = sigmoidf_(gxz[r] + bgz[r] + a1[r]);
      float nn = tanhf_(gxn[r] + bgn[r] + rr * (a2[r] + bhn[r]));
      h[r] = (1.f - zz) * nn + zz * h[r];
      hb16[r] = f2bf(h[r]);
    }
    u32 pk0 = (u32)hb16[0] | ((u32)hb16[1] << 16);
    u32 pk1 = (u32)hb16[2] | ((u32)hb16[3] << 16);

    // 4. publish: two self-validating u64 packets (fire-and-forget)
    if (sig < 511) {
      const u64 tagbits = (u64)(u32)(sig + 1) << 32;
      const u32 pb = (u32)((sig + 1) & 1) * 16384u + wb0;
      __hip_atomic_store(hex + pb,        tagbits | pk0, __ATOMIC_RELAXED, __HIP_MEMORY_SCOPE_AGENT);
      __hip_atomic_store(hex + pb + 128u, tagbits | pk1, __ATOMIC_RELAXED, __HIP_MEMORY_SCOPE_AGENT);
    }

    // 5. y output
    if (YF32) {
      f32x4 yv; yv.x = h[0]; yv.y = h[1]; yv.z = h[2]; yv.w = h[3];
      *(f32x4*)((float*)yout + ((size_t)(b * TT + t) * 1024 + d * 512 + u0)) = yv;
    } else {
      size_t o = (((size_t)(b * 32 + (t >> 4)) * 32 + (d * 16 + s)) * 64 + (l4 * 16 + (t & 15))) * 8 + 4 * uh;
      u32x2 pk; pk.x = pk0; pk.y = pk1;
      *(u32x2*)((u16*)yout + o) = pk;
    }
    if (sig == 511) {
      f32x4 fv; fv.x = h[0]; fv.y = h[1]; fv.z = h[2]; fv.w = h[3];
      *(f32x4*)(finals + (size_t)b * 1024 + d * 512 + u0) = fv;
      break;
    }

    // 6. gx prefetch for sig+1 (drains inside next poll's first wait — overlapped)
    {
      const int t2 = d ? (511 - (sig + 1)) : (sig + 1);
      const size_t base = ((size_t)(d * TT + t2) * BB + b) * GG + u0;
      if (GXF32) {
        const float* Gp = (const float*)gx_ + base;
        f32x4 vr = *(const f32x4*)(Gp);
        f32x4 vz = *(const f32x4*)(Gp + 512);
        f32x4 vn = *(const f32x4*)(Gp + 1024);
#pragma unroll
        for (int r = 0; r < 4; ++r) { gxr[r] = vr[r]; gxz[r] = vz[r]; gxn[r] = vn[r]; }
      } else {
        const u32* Gp = (const u32*)((const u16*)gx_ + base);
        u32 vr0 = Gp[0], vr1 = Gp[1], vz0 = Gp[256], vz1 = Gp[257], vn0 = Gp[512], vn1 = Gp[513];
        gxr[0] = bf2f((u16)vr0); gxr[1] = bf2f((u16)(vr0 >> 16)); gxr[2] = bf2f((u16)vr1); gxr[3] = bf2f((u16)(vr1 >> 16));
        gxz[0] = bf2f((u16)vz0); gxz[1] = bf2f((u16)(vz0 >> 16)); gxz[2] = bf2f((u16)vz1); gxz[3] = bf2f((u16)(vz1 >> 16));
        gxn[0] = bf2f((u16)vn0); gxn[1] = bf2f((u16)(vn0 >> 16)); gxn[2] = bf2f((u16)vn1); gxn[3] = bf2f((u16)(vn1 >> 16));
      }
    }
  }
}

// ---------------------------------------------------------------------------
extern "C" void kernel_launch(void* const* d_in, const int* in_sizes, int n_in,
                              void* d_out, int out_size, void* d_ws, size_t ws_size,
                              hipStream_t stream) {
  (void)in_sizes; (void)n_in; (void)out_size;
  const float* ctx   = (const float*)d_in[0];
  const float* wih0  = (const float*)d_in[1];
  const float* whh0  = (const float*)d_in[2];
  const float* bih0  = (const float*)d_in[3];
  const float* bhh0  = (const float*)d_in[4];
  const float* wih0r = (const float*)d_in[5];
  const float* whh0r = (const float*)d_in[6];
  const float* bih0r = (const float*)d_in[7];
  const float* bhh0r = (const float*)d_in[8];
  const float* wih1  = (const float*)d_in[9];
  const float* whh1  = (const float*)d_in[10];
  const float* bih1  = (const float*)d_in[11];
  const float* bhh1  = (const float*)d_in[12];
  const float* wih1r = (const float*)d_in[13];
  const float* whh1r = (const float*)d_in[14];
  const float* bih1r = (const float*)d_in[15];
  const float* bhh1r = (const float*)d_in[16];

  char* ws = (char*)d_ws;
  size_t off = 0;
  auto take = [&](size_t bytes) { char* p = ws + off; off += bytes; return p; };
  u16*   a0f  = (u16*)take(16777216);    // A0 frags
  u16*   a1f  = (u16*)take(33554432);    // A1 frags
  u16*   w0f  = (u16*)take(3145728);     // W0 frags
  u16*   w1f  = (u16*)take(6291456);     // W1 frags
  u16*   whhb = (u16*)take(6291456);     // w_hh bf16 [2][2][1536][512]
  float* bgx  = (float*)take(24576);     // [2][2][1536]
  float* bhn  = (float*)take(8192);      // [2][2][512]
  u64*   hexA = (u64*)take(262144);      // recur0 tagged slots (32768 u64)
  u64*   hexB = (u64*)take(262144);      // recur1 tagged slots
  const size_t GXF32_BYTES = 201326592;  // 2*512*32*1536*4
  const size_t GXB16_BYTES = 100663296;
  bool gxf32 = (ws_size >= off + GXF32_BYTES);
  void* gx = (void*)take(gxf32 ? GXF32_BYTES : GXB16_BYTES);

  PrepP P;
  P.ctx = ctx;
  P.wih0 = wih0; P.whh0 = whh0; P.bih0 = bih0; P.bhh0 = bhh0;
  P.wih0r = wih0r; P.whh0r = whh0r; P.bih0r = bih0r; P.bhh0r = bhh0r;
  P.wih1 = wih1; P.whh1 = whh1; P.bih1 = bih1; P.bhh1 = bhh1;
  P.wih1r = wih1r; P.whh1r = whh1r; P.bih1r = bih1r; P.bhh1r = bhh1r;
  P.a0f = a0f; P.w0f = w0f; P.w1f = w1f; P.whh = whhb;
  P.bgx = bgx; P.bhn = bhn; P.hexq = hexA;   // zeroes hexA+hexB (contiguous)

  prep_kernel<<<dim3(2048), dim3(256), 0, stream>>>(P);

  float* fin = (float*)d_out + (size_t)MM * 1024;
  if (gxf32) {
    proj_kernel<true><<<dim3(128, 24), dim3(256), 0, stream>>>(a0f, w0f, gx, 16);
    recur_kernel<true, false><<<dim3(32), dim3(256), 0, stream>>>(
        gx, whhb, bgx, bhn, a1f, fin, hexA);
    proj_kernel<true><<<dim3(128, 24), dim3(256), 0, stream>>>(a1f, w1f, gx, 32);
    recur_kernel<true, true><<<dim3(32), dim3(256), 0, stream>>>(
        gx, whhb + (size_t)2 * GG * HH, bgx + 2 * GG, bhn + 2 * HH, d_out, fin + 32768, hexB);
  } else {
    proj_kernel<false><<<dim3(128, 24), dim3(256), 0, stream>>>(a0f, w0f, gx, 16);
    recur_kernel<false, false><<<dim3(32), dim3(256), 0, stream>>>(
        gx, whhb, bgx, bhn, a1f, fin, hexA);
    proj_kernel<false><<<dim3(128, 24), dim3(256), 0, stream>>>(a1f, w1f, gx, 32);
    recur_kernel<false, true><<<dim3(32), dim3(256), 0, stream>>>(
        gx, whhb + (size_t)2 * GG * HH, bgx + 2 * GG, bhn + 2 * HH, d_out, fin + 32768, hexB);
  }
}

// Round 10
// 3017.784 us; speedup vs baseline: 1.4948x; 1.4948x over previous
//
#include <hip/hip_runtime.h>

typedef unsigned int  u32;
typedef unsigned long long u64;
typedef unsigned short u16;
typedef short s16x8 __attribute__((ext_vector_type(8)));
typedef float f32x4 __attribute__((ext_vector_type(4)));
typedef u32 u32x2 __attribute__((ext_vector_type(2)));
typedef u32 u32x4 __attribute__((ext_vector_type(4)));

// Problem constants
#define BB 32
#define TT 512
#define HH 512
#define GG 1536          // 3H
#define MM 16384         // B*T

#define TAGMASK 0x4000400040004000ull   // bit14 of each bf16 lane (always 0 for |h|<2)

__device__ __forceinline__ u16 f2bf(float f) {
  u32 u = __builtin_bit_cast(u32, f);
  u = u + 0x7FFFu + ((u >> 16) & 1u);   // RNE
  return (u16)(u >> 16);
}
__device__ __forceinline__ float bf2f(u16 h) {
  return __builtin_bit_cast(float, (u32)h << 16);
}
__device__ __forceinline__ float sigmoidf_(float x) { return 1.f / (1.f + __expf(-x)); }
__device__ __forceinline__ float tanhf_(float x)    { return 1.f - 2.f / (__expf(2.f * x) + 1.f); }

// 4-bit tag (step mod 16) spread over the four bit14 positions of a u64.
__device__ __forceinline__ u64 tagpat(u32 sig) {
  u64 t = (u64)(sig & 15u);
  return ((t & 1) << 14) | (((t >> 1) & 1) << 30) | (((t >> 2) & 1) << 46) | (((t >> 3) & 1) << 62);
}

// ---------------------------------------------------------------------------
// Fragment layout convention (mfma_f32_16x16x32_bf16), used consistently
// everywhere (any consistent K-permutation of A and B cancels):
//   A (MxK): lane l elem j -> A[16*mb + (l&15)][32*kb + (l>>4)*4 + (j&3) + 16*(j>>2)]
//   B (KxN): lane l elem j -> B[32*kb + (l>>4)*4 + (j&3) + 16*(j>>2)][16*nb + (l&15)]
//   D:       lane l reg  r -> D[(l>>4)*4 + r][l&15]            (m89-verified)
// ---------------------------------------------------------------------------

struct PrepP {
  const float *ctx;
  const float *wih0, *whh0, *bih0, *bhh0, *wih0r, *whh0r, *bih0r, *bhh0r;
  const float *wih1, *whh1, *bih1, *bhh1, *wih1r, *whh1r, *bih1r, *bhh1r;
  u16 *a0f, *w0f, *w1f, *whh;
  float *bgx, *bhn;
  u64 *hexq;
};

__global__ void prep_kernel(PrepP P) {
  const size_t NA0 = (size_t)MM * 512;          // A0 frags
  const size_t NW0 = (size_t)3072 * 512;        // W0 frags
  const size_t NW1 = (size_t)3072 * 1024;       // W1 frags
  const size_t NWH = (size_t)2 * 2 * GG * HH;   // w_hh bf16 copies
  const size_t NBG = 2 * 2 * (size_t)GG;
  const size_t NBN = 2 * 2 * (size_t)HH;
  const size_t NHX = 32768;                     // 2 recurs x 16384 tagged u64 slots
  const size_t TOTAL = NA0 + NW0 + NW1 + NWH + NBG + NBN + NHX;
  size_t stride = (size_t)gridDim.x * blockDim.x;
  for (size_t i = (size_t)blockIdx.x * blockDim.x + threadIdx.x; i < TOTAL; i += stride) {
    size_t e = i;
    if (e < NA0) {
      int j = e & 7, l = (e >> 3) & 63, kb = (e >> 9) & 15, mb = (int)(e >> 13);
      int m = mb * 16 + (l & 15);
      int k = kb * 32 + ((l >> 4) << 2) + (j & 3) + ((j >> 2) << 4);
      P.a0f[e] = f2bf(P.ctx[(size_t)m * 512 + k]);
      continue;
    }
    e -= NA0;
    if (e < NW0) {
      int j = e & 7, l = (e >> 3) & 63, kb = (e >> 9) & 15, nb = (int)(e >> 13);
      int n = nb * 16 + (l & 15);
      int d = (n >= GG) ? 1 : 0, g = n - d * GG;
      int k = kb * 32 + ((l >> 4) << 2) + (j & 3) + ((j >> 2) << 4);
      const float* src = d ? P.wih0r : P.wih0;
      P.w0f[e] = f2bf(src[(size_t)g * 512 + k]);
      continue;
    }
    e -= NW0;
    if (e < NW1) {
      int j = e & 7, l = (e >> 3) & 63, kb = (e >> 9) & 31, nb = (int)(e >> 14);
      int n = nb * 16 + (l & 15);
      int d = (n >= GG) ? 1 : 0, g = n - d * GG;
      int k = kb * 32 + ((l >> 4) << 2) + (j & 3) + ((j >> 2) << 4);
      const float* src = d ? P.wih1r : P.wih1;
      P.w1f[e] = f2bf(src[(size_t)g * 1024 + k]);
      continue;
    }
    e -= NW1;
    if (e < NWH) {
      size_t per = (size_t)GG * HH;
      int ld = (int)(e / per); size_t sub = e % per;
      const float* src = (ld == 0) ? P.whh0 : (ld == 1) ? P.whh0r : (ld == 2) ? P.whh1 : P.whh1r;
      P.whh[e] = f2bf(src[sub]);
      continue;
    }
    e -= NWH;
    if (e < NBG) {
      int ld = (int)(e / GG), g = (int)(e % GG);
      const float* bi = (ld == 0) ? P.bih0 : (ld == 1) ? P.bih0r : (ld == 2) ? P.bih1 : P.bih1r;
      const float* bh = (ld == 0) ? P.bhh0 : (ld == 1) ? P.bhh0r : (ld == 2) ? P.bhh1 : P.bhh1r;
      P.bgx[e] = bi[g] + ((g < 1024) ? bh[g] : 0.f);
      continue;
    }
    e -= NBG;
    if (e < NBN) {
      int ld = (int)(e / HH), u = (int)(e % HH);
      const float* bh = (ld == 0) ? P.bhh0 : (ld == 1) ? P.bhh0r : (ld == 2) ? P.bhh1 : P.bhh1r;
      P.bhn[e] = bh[1024 + u];
      continue;
    }
    e -= NBN;
    if (e < NHX) { P.hexq[e] = 0ull; continue; }   // tag nibble 0 (collision-free, see proof)
  }
}

// ---------------------------------------------------------------------------
// Projection GEMM (unchanged, proven): C[16384][3072] = A*W, bf16 MFMA.
// ---------------------------------------------------------------------------
template<bool GXF32>
__global__ __launch_bounds__(256, 2) void proj_kernel(const u16* __restrict__ A,
                                                      const u16* __restrict__ W,
                                                      void* __restrict__ gx, int KB) {
  __shared__ uint4 As4[512];
  __shared__ uint4 Bs4[512];
  const int tid = threadIdx.x;
  const int bm = blockIdx.x, bn = blockIdx.y;
  const int l = tid & 63, w = tid >> 6, wm = w >> 1, wn = w & 1;

  f32x4 acc[4][4];
#pragma unroll
  for (int i = 0; i < 4; ++i)
#pragma unroll
    for (int j = 0; j < 4; ++j) acc[i][j] = f32x4{0.f, 0.f, 0.f, 0.f};

  const uint4* GA = (const uint4*)A;
  const uint4* GB = (const uint4*)W;

  for (int kt = 0; kt < KB; ++kt) {
    __syncthreads();
#pragma unroll
    for (int c = 0; c < 2; ++c) {
      int idx = tid * 2 + c;
      int blk = idx >> 6, pos = idx & 63;
      As4[idx] = GA[((size_t)(bm * 8 + blk) * KB + kt) * 64 + pos];
      Bs4[idx] = GB[((size_t)(bn * 8 + blk) * KB + kt) * 64 + pos];
    }
    __syncthreads();
    s16x8 av[4], bv[4];
#pragma unroll
    for (int mf = 0; mf < 4; ++mf) av[mf] = ((const s16x8*)As4)[(wm * 4 + mf) * 64 + l];
#pragma unroll
    for (int nf = 0; nf < 4; ++nf) bv[nf] = ((const s16x8*)Bs4)[(wn * 4 + nf) * 64 + l];
#pragma unroll
    for (int mf = 0; mf < 4; ++mf)
#pragma unroll
      for (int nf = 0; nf < 4; ++nf)
        acc[mf][nf] = __builtin_amdgcn_mfma_f32_16x16x32_bf16(av[mf], bv[nf], acc[mf][nf], 0, 0, 0);
  }

#pragma unroll
  for (int mf = 0; mf < 4; ++mf)
#pragma unroll
    for (int nf = 0; nf < 4; ++nf)
#pragma unroll
      for (int r = 0; r < 4; ++r) {
        int m = bm * 128 + wm * 64 + mf * 16 + (l >> 4) * 4 + r;
        int n = bn * 128 + wn * 64 + nf * 16 + (l & 15);
        int b = m >> 9, t = m & 511;
        int d = (n >= GG) ? 1 : 0, g = n - d * GG;
        size_t o = ((size_t)(d * TT + t) * BB + b) * GG + g;
        float v = acc[mf][nf][r];
        if (GXF32) ((float*)gx)[o] = v;
        else       ((u16*)gx)[o] = f2bf(v);
      }
}

// ---------------------------------------------------------------------------
// Recurrence: 32 WGs (16/dir).  Single-transaction transport: each producer
// lane publishes ONE relaxed atomic u64 = {4 x bf16 h} with a 4-bit step tag
// hidden in the four bit14 positions (|h|<1 -> bit14 always 0).  Packets are
// self-validating: no ack, no flag, no fence.  Consumer polls its 32 input
// packets (own nt-half, coalesced: consecutive lanes -> consecutive u64) with
// relaxed agent atomic loads (the proven-fresh primitive); on tag match the
// data is already in registers -> strip tags -> MFMA.
// Overwrite safety: producer rewrites a slot (tag sig+2) only after observing
// all own-nt waves' tag sig+1 packets, which data-depend on their tag-sig
// reads -> no consumer can see a torn generation.  Tag mod 16: fresh(sig) vs
// stale(sig-2) vs initial(0) never collide (first writes have tags 1,2).
// Slot index: [buf(2)][d(2)][q=s*2+uh (32)][nt(2)][lane(64)] u64.
// ---------------------------------------------------------------------------
template<bool GXF32, bool YF32>
__global__ __launch_bounds__(256, 1) void recur_kernel(
    const void* __restrict__ gx_, const u16* __restrict__ whh,
    const float* __restrict__ bgx, const float* __restrict__ bhn_,
    void* __restrict__ yout, float* __restrict__ finals,
    u64* __restrict__ hex) {
  const int wg = blockIdx.x, d = wg >> 4, s = wg & 15;
  const int tid = threadIdx.x, l = tid & 63, w = tid >> 6;
  const int nt = w & 1, uh = w >> 1;
  const int l4 = l >> 4, lm = l & 15;
  const int b = nt * 16 + lm;
  const int u0 = s * 32 + uh * 16 + l4 * 4;   // first of this lane's 4 h-units

  // --- w_hh A-fragments into registers ---
  s16x8 af[3][16];
  const u16* wd = whh + (size_t)d * (GG * HH);
#pragma unroll
  for (int g = 0; g < 3; ++g) {
    const int row = g * 512 + s * 32 + uh * 16 + lm;   // A-side row uses lane&15
    const u16* rp = wd + (size_t)row * 512 + l4 * 4;
#pragma unroll
    for (int ks = 0; ks < 16; ++ks) {
      u32 lo0 = *(const u32*)(rp + ks * 32);
      u32 lo1 = *(const u32*)(rp + ks * 32 + 2);
      u32 hi0 = *(const u32*)(rp + ks * 32 + 16);
      u32 hi1 = *(const u32*)(rp + ks * 32 + 18);
      u32x4 t4; t4.x = lo0; t4.y = lo1; t4.z = hi0; t4.w = hi1;
      af[g][ks] = __builtin_bit_cast(s16x8, t4);
    }
  }
  float bgr[4], bgz[4], bgn[4], bhn[4];
#pragma unroll
  for (int r = 0; r < 4; ++r) {
    bgr[r] = bgx[d * GG + 0 * 512 + u0 + r];
    bgz[r] = bgx[d * GG + 1 * 512 + u0 + r];
    bgn[r] = bgx[d * GG + 2 * 512 + u0 + r];
    bhn[r] = bhn_[d * HH + u0 + r];
  }
  float h[4] = {0.f, 0.f, 0.f, 0.f};

  // slot indices (u64): buf stride 8192, d stride 4096, q stride 128, nt 64
  const u32 wslot = (u32)(d * 4096 + (s * 2 + uh) * 128 + nt * 64 + l);
  const u32 rbase = (u32)(d * 4096 + nt * 64 + l);

  // gx registers, prologue load for sig=0
  float gxr[4], gxz[4], gxn[4];
  {
    const int t0 = d ? 511 : 0;
    const size_t base = ((size_t)(d * TT + t0) * BB + b) * GG + u0;
    if (GXF32) {
      const float* Gp = (const float*)gx_ + base;
      f32x4 vr = *(const f32x4*)(Gp);
      f32x4 vz = *(const f32x4*)(Gp + 512);
      f32x4 vn = *(const f32x4*)(Gp + 1024);
#pragma unroll
      for (int r = 0; r < 4; ++r) { gxr[r] = vr[r]; gxz[r] = vz[r]; gxn[r] = vn[r]; }
    } else {
      const u32* Gp = (const u32*)((const u16*)gx_ + base);
      u32 vr0 = Gp[0], vr1 = Gp[1], vz0 = Gp[256], vz1 = Gp[257], vn0 = Gp[512], vn1 = Gp[513];
      gxr[0] = bf2f((u16)vr0); gxr[1] = bf2f((u16)(vr0 >> 16)); gxr[2] = bf2f((u16)vr1); gxr[3] = bf2f((u16)(vr1 >> 16));
      gxz[0] = bf2f((u16)vz0); gxz[1] = bf2f((u16)(vz0 >> 16)); gxz[2] = bf2f((u16)vz1); gxz[3] = bf2f((u16)(vz1 >> 16));
      gxn[0] = bf2f((u16)vn0); gxn[1] = bf2f((u16)(vn0 >> 16)); gxn[2] = bf2f((u16)vn1); gxn[3] = bf2f((u16)(vn1 >> 16));
    }
  }

  for (int sig = 0; sig < 512; ++sig) {
    const int t = d ? (511 - sig) : sig;

    f32x4 a0 = {0.f, 0.f, 0.f, 0.f}, a1 = a0, a2 = a0;
    if (sig > 0) {
      // 1. poll+data: 32 tagged u64 packets (own nt-half) from buf[sig&1]
      const u32 cb = (u32)(sig & 1) * 8192u + rbase;
      const u64 pat = tagpat((u32)sig);
      u64 v[32];
      while (true) {
#pragma unroll
        for (int q = 0; q < 32; ++q)
          v[q] = __hip_atomic_load(hex + cb + (u32)q * 128u,
                                   __ATOMIC_RELAXED, __HIP_MEMORY_SCOPE_AGENT);
        u32 good = 1u;
#pragma unroll
        for (int q = 0; q < 32; ++q)
          good &= (u32)(((v[q] ^ pat) & TAGMASK) == 0ull);
        if (__all((int)good)) break;
      }
      __builtin_amdgcn_sched_barrier(0);

      // 2. strip tags + MFMA: fragment ks <- packets q=2ks (uh'=0), 2ks+1 (uh'=1)
#pragma unroll
      for (int ks = 0; ks < 16; ++ks) {
        u64 m0 = v[ks * 2]     & ~TAGMASK;
        u64 m1 = v[ks * 2 + 1] & ~TAGMASK;
        u32x4 t4;
        t4.x = (u32)m0; t4.y = (u32)(m0 >> 32);
        t4.z = (u32)m1; t4.w = (u32)(m1 >> 32);
        s16x8 bv = __builtin_bit_cast(s16x8, t4);
        a0 = __builtin_amdgcn_mfma_f32_16x16x32_bf16(af[0][ks], bv, a0, 0, 0, 0);
        a1 = __builtin_amdgcn_mfma_f32_16x16x32_bf16(af[1][ks], bv, a1, 0, 0, 0);
        a2 = __builtin_amdgcn_mfma_f32_16x16x32_bf16(af[2][ks], bv, a2, 0, 0, 0);
      }
    }

    // 3. gates
    u16 hb16[4];
#pragma unroll
    for (int r = 0; r < 4; ++r) {
      float rr = sigmoidf_(gxr[r] + bgr[r] + a0[r]);
      float zz = sigmoidf_(gxz[r] + bgz[r] + a1[r]);
      float nn = tanhf_(gxn[r] + bgn[r] + rr * (a2[r] + bhn[r]));
      h[r] = (1.f - zz) * nn + zz * h[r];
      hb16[r] = f2bf(h[r]);
    }
    u32 pk0 = (u32)hb16[0] | ((u32)hb16[1] << 16);
    u32 pk1 = (u32)hb16[2] | ((u32)hb16[3] << 16);

    // 4. publish: ONE self-validating u64 packet, fire-and-forget
    if (sig < 511) {
      u64 pk = ((u64)pk0 | ((u64)pk1 << 32)) | tagpat((u32)(sig + 1));
      __hip_atomic_store(hex + (u32)((sig + 1) & 1) * 8192u + wslot, pk,
                         __ATOMIC_RELAXED, __HIP_MEMORY_SCOPE_AGENT);
    }

    // 5. y output
    if (YF32) {
      f32x4 yv; yv.x = h[0]; yv.y = h[1]; yv.z = h[2]; yv.w = h[3];
      *(f32x4*)((float*)yout + ((size_t)(b * TT + t) * 1024 + d * 512 + u0)) = yv;
    } else {
      size_t o = (((size_t)(b * 32 + (t >> 4)) * 32 + (d * 16 + s)) * 64 + (l4 * 16 + (t & 15))) * 8 + 4 * uh;
      u32x2 pk; pk.x = pk0; pk.y = pk1;
      *(u32x2*)((u16*)yout + o) = pk;
    }
    if (sig == 511) {
      f32x4 fv; fv.x = h[0]; fv.y = h[1]; fv.z = h[2]; fv.w = h[3];
      *(f32x4*)(finals + (size_t)b * 1024 + d * 512 + u0) = fv;
      break;
    }

    // 6. gx prefetch for sig+1 (drains during next poll — overlapped with producers)
    {
      const int t2 = d ? (511 - (sig + 1)) : (sig + 1);
      const size_t base = ((size_t)(d * TT + t2) * BB + b) * GG + u0;
      if (GXF32) {
        const float* Gp = (const float*)gx_ + base;
        f32x4 vr = *(const f32x4*)(Gp);
        f32x4 vz = *(const f32x4*)(Gp + 512);
        f32x4 vn = *(const f32x4*)(Gp + 1024);
#pragma unroll
        for (int r = 0; r < 4; ++r) { gxr[r] = vr[r]; gxz[r] = vz[r]; gxn[r] = vn[r]; }
      } else {
        const u32* Gp = (const u32*)((const u16*)gx_ + base);
        u32 vr0 = Gp[0], vr1 = Gp[1], vz0 = Gp[256], vz1 = Gp[257], vn0 = Gp[512], vn1 = Gp[513];
        gxr[0] = bf2f((u16)vr0); gxr[1] = bf2f((u16)(vr0 >> 16)); gxr[2] = bf2f((u16)vr1); gxr[3] = bf2f((u16)(vr1 >> 16));
        gxz[0] = bf2f((u16)vz0); gxz[1] = bf2f((u16)(vz0 >> 16)); gxz[2] = bf2f((u16)vz1); gxz[3] = bf2f((u16)(vz1 >> 16));
        gxn[0] = bf2f((u16)vn0); gxn[1] = bf2f((u16)(vn0 >> 16)); gxn[2] = bf2f((u16)vn1); gxn[3] = bf2f((u16)(vn1 >> 16));
      }
    }
  }
}

// ---------------------------------------------------------------------------
extern "C" void kernel_launch(void* const* d_in, const int* in_sizes, int n_in,
                              void* d_out, int out_size, void* d_ws, size_t ws_size,
                              hipStream_t stream) {
  (void)in_sizes; (void)n_in; (void)out_size;
  const float* ctx   = (const float*)d_in[0];
  const float* wih0  = (const float*)d_in[1];
  const float* whh0  = (const float*)d_in[2];
  const float* bih0  = (const float*)d_in[3];
  const float* bhh0  = (const float*)d_in[4];
  const float* wih0r = (const float*)d_in[5];
  const float* whh0r = (const float*)d_in[6];
  const float* bih0r = (const float*)d_in[7];
  const float* bhh0r = (const float*)d_in[8];
  const float* wih1  = (const float*)d_in[9];
  const float* whh1  = (const float*)d_in[10];
  const float* bih1  = (const float*)d_in[11];
  const float* bhh1  = (const float*)d_in[12];
  const float* wih1r = (const float*)d_in[13];
  const float* whh1r = (const float*)d_in[14];
  const float* bih1r = (const float*)d_in[15];
  const float* bhh1r = (const float*)d_in[16];

  char* ws = (char*)d_ws;
  size_t off = 0;
  auto take = [&](size_t bytes) { char* p = ws + off; off += bytes; return p; };
  u16*   a0f  = (u16*)take(16777216);    // A0 frags
  u16*   a1f  = (u16*)take(33554432);    // A1 frags
  u16*   w0f  = (u16*)take(3145728);     // W0 frags
  u16*   w1f  = (u16*)take(6291456);     // W1 frags
  u16*   whhb = (u16*)take(6291456);     // w_hh bf16 [2][2][1536][512]
  float* bgx  = (float*)take(24576);     // [2][2][1536]
  float* bhn  = (float*)take(8192);      // [2][2][512]
  u64*   hexA = (u64*)take(131072);      // recur0 tagged slots (16384 u64)
  u64*   hexB = (u64*)take(131072);      // recur1 tagged slots
  const size_t GXF32_BYTES = 201326592;  // 2*512*32*1536*4
  const size_t GXB16_BYTES = 100663296;
  bool gxf32 = (ws_size >= off + GXF32_BYTES);
  void* gx = (void*)take(gxf32 ? GXF32_BYTES : GXB16_BYTES);

  PrepP P;
  P.ctx = ctx;
  P.wih0 = wih0; P.whh0 = whh0; P.bih0 = bih0; P.bhh0 = bhh0;
  P.wih0r = wih0r; P.whh0r = whh0r; P.bih0r = bih0r; P.bhh0r = bhh0r;
  P.wih1 = wih1; P.whh1 = whh1; P.bih1 = bih1; P.bhh1 = bhh1;
  P.wih1r = wih1r; P.whh1r = whh1r; P.bih1r = bih1r; P.bhh1r = bhh1r;
  P.a0f = a0f; P.w0f = w0f; P.w1f = w1f; P.whh = whhb;
  P.bgx = bgx; P.bhn = bhn; P.hexq = hexA;   // zeroes hexA+hexB (contiguous)

  prep_kernel<<<dim3(2048), dim3(256), 0, stream>>>(P);

  float* fin = (float*)d_out + (size_t)MM * 1024;
  if (gxf32) {
    proj_kernel<true><<<dim3(128, 24), dim3(256), 0, stream>>>(a0f, w0f, gx, 16);
    recur_kernel<true, false><<<dim3(32), dim3(256), 0, stream>>>(
        gx, whhb, bgx, bhn, a1f, fin, hexA);
    proj_kernel<true><<<dim3(128, 24), dim3(256), 0, stream>>>(a1f, w1f, gx, 32);
    recur_kernel<true, true><<<dim3(32), dim3(256), 0, stream>>>(
        gx, whhb + (size_t)2 * GG * HH, bgx + 2 * GG, bhn + 2 * HH, d_out, fin + 32768, hexB);
  } else {
    proj_kernel<false><<<dim3(128, 24), dim3(256), 0, stream>>>(a0f, w0f, gx, 16);
    recur_kernel<false, false><<<dim3(32), dim3(256), 0, stream>>>(
        gx, whhb, bgx, bhn, a1f, fin, hexA);
    proj_kernel<false><<<dim3(128, 24), dim3(256), 0, stream>>>(a1f, w1f, gx, 32);
    recur_kernel<false, true><<<dim3(32), dim3(256), 0, stream>>>(
        gx, whhb + (size_t)2 * GG * HH, bgx + 2 * GG, bhn + 2 * HH, d_out, fin + 32768, hexB);
  }
}